// Round 9
// baseline (257.433 us; speedup 1.0000x reference)
//
#include <hip/hip_runtime.h>
#include <cfloat>
#include <cmath>

#define DEVINL __device__ __forceinline__

constexpr int N_ = 4, C_ = 21, H_ = 512, W_ = 512;
constexpr int P_ = 171;           // pooled H/W
constexpr int Q_ = 169;           // point grid: P-3+1
constexpr int NC_ = N_ * C_;      // 84
constexpr int HW_ = H_ * W_;      // 262144 = 2^18
constexpr int PP_ = 29241;        // P_*P_ (pack layout, unpadded)
constexpr int PROW_ = 172;        // padded row stride for pr/la (16B-aligned rows)
constexpr int PPAD_ = PROW_ * P_; // 29412 per (n,c) image
constexpr int NCOV_ = 189;        // 9 + 9 + 45 + 45 + 81
constexpr float EPS_ = 5e-4f;
constexpr int RC_ = 29;           // point-rows per k_cov chunk (6 chunks cover 169)
constexpr int G_ = 43;            // col-quads per row
constexpr int SROW_ = 176;        // LDS row stride (16B-aligned, room for x0=168 b128 reads)

DEVINL constexpr int tstart(int d) { return d * 9 - d * (d - 1) / 2; }

DEVINL float wave_sum(float v) {
#pragma unroll
    for (int o = 32; o > 0; o >>= 1) v += __shfl_down(v, o, 64);
    return v;
}

// ---------------------------------------------------------------------------
// k_bits: thread per pooled cell (n,i,j). UNCHANGED.
// ---------------------------------------------------------------------------
__global__ __launch_bounds__(256) void k_bits(const int* __restrict__ target,
                                              unsigned* __restrict__ pack) {
    int tid = blockIdx.x * 256 + threadIdx.x;
    if (tid >= N_ * PP_) return;
    int cell = tid % PP_;
    int n = tid / PP_;
    int j = cell % P_;
    int i = cell / P_;
    int hl = 3 * i - 1; if (hl < 0) hl = 0;
    int wl = 3 * j - 1; if (wl < 0) wl = 0;
    int hmax = 3 * i + 1, wmax = 3 * j + 1;
    const int* tb = target + (size_t)n * HW_;
    unsigned oh = 0, px = 0;
#pragma unroll
    for (int r = 0; r < 3; ++r) {
        int hh = hl + r;
        bool hv = hh <= hmax;
        const int* trow = tb + hh * W_;
#pragma unroll
        for (int dc = 0; dc < 3; ++dc) {
            int ww = wl + dc;
            int t = trow[ww];
            if (hv && (ww <= wmax) && t >= 0 && t < C_) {
                oh |= 1u << t;
                px |= 1u << (r * 3 + dc);
            }
        }
    }
    pack[tid] = oh | (px << 23);
}

// ---------------------------------------------------------------------------
// k_ce v2: thread per 4 pixels, 21 float4 loads live in registers. UNCHANGED.
// ---------------------------------------------------------------------------
__global__ __launch_bounds__(256) void k_ce(const float* __restrict__ score,
                                            const int* __restrict__ target,
                                            float* __restrict__ cov_ce) {
    int tid = blockIdx.x * 256 + threadIdx.x;
    int p0 = tid * 4;
    int n = p0 >> 18;
    int hw = p0 & (HW_ - 1);
    const float* sp = score + (size_t)n * C_ * HW_ + hw;

    float4 s[C_];
#pragma unroll
    for (int c = 0; c < C_; ++c)
        s[c] = *(const float4*)(sp + (size_t)c * HW_);
    int4 t4 = *(const int4*)(target + p0);

    float4 se = {0.f, 0.f, 0.f, 0.f};
    float4 stgt = {0.f, 0.f, 0.f, 0.f};
#pragma unroll
    for (int c = 0; c < C_; ++c) {
        se.x += __expf(s[c].x);
        se.y += __expf(s[c].y);
        se.z += __expf(s[c].z);
        se.w += __expf(s[c].w);
        if (t4.x == c) stgt.x = s[c].x;
        if (t4.y == c) stgt.y = s[c].y;
        if (t4.z == c) stgt.z = s[c].z;
        if (t4.w == c) stgt.w = s[c].w;
    }
    float nll = 0.f, cnt = 0.f;
    if (t4.x != 255) { nll += __logf(se.x) - stgt.x; cnt += 1.f; }
    if (t4.y != 255) { nll += __logf(se.y) - stgt.y; cnt += 1.f; }
    if (t4.z != 255) { nll += __logf(se.z) - stgt.z; cnt += 1.f; }
    if (t4.w != 255) { nll += __logf(se.w) - stgt.w; cnt += 1.f; }

    nll = wave_sum(nll);
    cnt = wave_sum(cnt);
    __shared__ float rn[4], rc[4];
    int wv = threadIdx.x >> 6, lane = threadIdx.x & 63;
    if (lane == 0) { rn[wv] = nll; rc[wv] = cnt; }
    __syncthreads();
    if (threadIdx.x == 0) {
        atomicAdd(&cov_ce[NC_ * NCOV_ + 0], rn[0] + rn[1] + rn[2] + rn[3]);
        atomicAdd(&cov_ce[NC_ * NCOV_ + 1], rc[0] + rc[1] + rc[2] + rc[3]);
    }
}

// ---------------------------------------------------------------------------
// k_pool v2: thread per (n,c,i,g), padded output stride. UNCHANGED.
// ---------------------------------------------------------------------------
template <int IDX>
DEVINL void do_cell(const float (&f)[3][16], unsigned pk, int c, float* prp, float* lap) {
    unsigned px = pk >> 23;
    float vm = -FLT_MAX;
#pragma unroll
    for (int r = 0; r < 3; ++r)
#pragma unroll
        for (int dc = 0; dc < 3; ++dc)
            vm = fmaxf(vm, ((px >> (r * 3 + dc)) & 1u) ? f[r][IDX + dc] : -FLT_MAX);
    float p = __builtin_amdgcn_rcpf(1.f + __expf(-vm));
    p = fminf(fmaxf(p, 1e-6f), 1.f);
    *prp = p;
    *lap = ((pk >> c) & 1u) ? 1.f : 0.f;
}

__global__ __launch_bounds__(256) void k_pool(const float* __restrict__ score,
                                              const unsigned* __restrict__ pack,
                                              float* __restrict__ pr,
                                              float* __restrict__ la) {
    int tid = blockIdx.x * 256 + threadIdx.x;
    if (tid >= NC_ * P_ * G_) return;
    int g = tid % G_;
    int rest = tid / G_;
    int i = rest % P_;
    int ncidx = rest / P_;
    int n = ncidx / C_;
    int c = ncidx - n * C_;

    int hl = 3 * i - 1; if (hl < 0) hl = 0;
    int b = (g == 0) ? 0 : 12 * g - 4;
    int o3 = (b + 15 < W_) ? 12 : 8;

    const float* sb = score + (size_t)ncidx * HW_ + (size_t)hl * W_ + b;
    float f[3][16];
#pragma unroll
    for (int r = 0; r < 3; ++r) {
        const float* rp = sb + r * W_;
        float4 q0 = *(const float4*)(rp);
        float4 q1 = *(const float4*)(rp + 4);
        float4 q2 = *(const float4*)(rp + 8);
        float4 q3 = *(const float4*)(rp + o3);
        f[r][0] = q0.x;  f[r][1] = q0.y;  f[r][2] = q0.z;  f[r][3] = q0.w;
        f[r][4] = q1.x;  f[r][5] = q1.y;  f[r][6] = q1.z;  f[r][7] = q1.w;
        f[r][8] = q2.x;  f[r][9] = q2.y;  f[r][10] = q2.z; f[r][11] = q2.w;
        f[r][12] = q3.x; f[r][13] = q3.y; f[r][14] = q3.z; f[r][15] = q3.w;
    }

    const unsigned* pkp = pack + n * PP_ + i * P_ + 4 * g;
    size_t ob = (size_t)ncidx * PPAD_ + (size_t)i * PROW_ + 4 * g;
    if (g == 0) {
        do_cell<0>(f, pkp[0], c, pr + ob + 0, la + ob + 0);
        do_cell<2>(f, pkp[1], c, pr + ob + 1, la + ob + 1);
        do_cell<5>(f, pkp[2], c, pr + ob + 2, la + ob + 2);
        do_cell<8>(f, pkp[3], c, pr + ob + 3, la + ob + 3);
    } else {
        do_cell<3>(f, pkp[0], c, pr + ob + 0, la + ob + 0);
        do_cell<6>(f, pkp[1], c, pr + ob + 1, la + ob + 1);
        do_cell<9>(f, pkp[2], c, pr + ob + 2, la + ob + 2);
        if (4 * g + 3 < P_)
            do_cell<12>(f, pkp[3], c, pr + ob + 3, la + ob + 3);
    }
}

// ---------------------------------------------------------------------------
// k_cov v5: block per (nc, chunk), 512 threads. Stage la+pr subgrid once in
// LDS (43.6 KB, float4 coalesced), one barrier, then 8 waves each accumulate
// a ~24-27-sum subset of the 189 sums from LDS (ds_read_b128; no latency
// exposure, no redundant global passes — R6-R8 all pinned at ~51-55us on
// per-part global re-reads + tiny main loops). Per-wave shuffle reduction +
// atomics, no further barriers.
//   w0: s1A + SAA d=0,1 | w1: SAA d=2..4 + SAB d=8 | w2: SAA d=5..8 + SAB d=7
//   w3: s1B + SBB d=0,1 | w4: SBB d=2..4 + SAB d=6 | w5: SBB d=5..8 + SAB d=5
//   w6: SAB d=0..2      | w7: SAB d=3,4
// grid = (84, 6), block = 512.
// ---------------------------------------------------------------------------
template <int D0, int D1, bool S1, int S1B, int S2B>
DEVINL void tri_lds(const float (*X)[SROW_], int nq, int lane,
                    float* __restrict__ cov, int nc) {
    constexpr int NP = ((9 - D0) * (10 - D0) - (9 - D1) * (10 - D1)) / 2;
    constexpr int NS = S1 ? 9 : 0;
    constexpr int RLO = D0 / 3;
    float acc[NS + NP];
#pragma unroll
    for (int k = 0; k < NS + NP; ++k) acc[k] = 0.f;

    for (int qi = lane; qi < nq; qi += 64) {
        int lr = qi / G_;
        int q = qi - lr * G_;
        int x0 = 4 * q;
        float v[3][8];
#pragma unroll
        for (int r = RLO; r < 3; ++r) {
            float4 u0 = *(const float4*)&X[lr + r][x0];
            float4 u1 = *(const float4*)&X[lr + r][x0 + 4];
            v[r][0] = u0.x; v[r][1] = u0.y; v[r][2] = u0.z; v[r][3] = u0.w;
            v[r][4] = u1.x; v[r][5] = u1.y; v[r][6] = u1.z; v[r][7] = u1.w;
        }
#pragma unroll
        for (int p = 0; p < 4; ++p) {
            if (x0 + p < Q_) {
                if constexpr (S1) {
#pragma unroll
                    for (int d = 0; d < 9; ++d) acc[d] += v[d / 3][p + d % 3];
                }
                int k = NS;
#pragma unroll
                for (int d = D0; d < D1; ++d)
#pragma unroll
                    for (int e = d; e < 9; ++e) {
                        acc[k] += v[d / 3][p + d % 3] * v[e / 3][p + e % 3];
                        ++k;
                    }
            }
        }
    }
#pragma unroll
    for (int k = 0; k < NS + NP; ++k) {
        float v2 = wave_sum(acc[k]);
        if (lane == 0) {
            int dst = (S1 && k < 9) ? (S1B + k) : (S2B + tstart(D0) + k - NS);
            atomicAdd(&cov[nc * NCOV_ + dst], v2);
        }
    }
}

template <int R0, int R1>
DEVINL void ab_lds(const float (*LA)[SROW_], const float (*PR)[SROW_],
                   int nq, int lane, float* __restrict__ cov, int nc) {
    constexpr int NA = (R1 - R0) * 9;
    constexpr int ALO = R0 / 3, AHI = (R1 - 1) / 3;
    float acc[NA];
#pragma unroll
    for (int k = 0; k < NA; ++k) acc[k] = 0.f;

    for (int qi = lane; qi < nq; qi += 64) {
        int lr = qi / G_;
        int q = qi - lr * G_;
        int x0 = 4 * q;
        float av[3][8], bv[3][8];
#pragma unroll
        for (int r = ALO; r <= AHI; ++r) {
            float4 u0 = *(const float4*)&LA[lr + r][x0];
            float4 u1 = *(const float4*)&LA[lr + r][x0 + 4];
            av[r][0] = u0.x; av[r][1] = u0.y; av[r][2] = u0.z; av[r][3] = u0.w;
            av[r][4] = u1.x; av[r][5] = u1.y; av[r][6] = u1.z; av[r][7] = u1.w;
        }
#pragma unroll
        for (int r = 0; r < 3; ++r) {
            float4 u0 = *(const float4*)&PR[lr + r][x0];
            float4 u1 = *(const float4*)&PR[lr + r][x0 + 4];
            bv[r][0] = u0.x; bv[r][1] = u0.y; bv[r][2] = u0.z; bv[r][3] = u0.w;
            bv[r][4] = u1.x; bv[r][5] = u1.y; bv[r][6] = u1.z; bv[r][7] = u1.w;
        }
#pragma unroll
        for (int p = 0; p < 4; ++p) {
            if (x0 + p < Q_) {
#pragma unroll
                for (int d = R0; d < R1; ++d)
#pragma unroll
                    for (int e = 0; e < 9; ++e)
                        acc[(d - R0) * 9 + e] += av[d / 3][p + d % 3] * bv[e / 3][p + e % 3];
            }
        }
    }
#pragma unroll
    for (int k = 0; k < NA; ++k) {
        float v2 = wave_sum(acc[k]);
        if (lane == 0)
            atomicAdd(&cov[nc * NCOV_ + 108 + R0 * 9 + k], v2);
    }
}

__global__ __launch_bounds__(512) void k_cov(const float* __restrict__ la,
                                             const float* __restrict__ pr,
                                             float* __restrict__ cov) {
    __shared__ float sLA[31][SROW_];
    __shared__ float sPR[31][SROW_];
    int nc = blockIdx.x;
    int chunk = blockIdx.y;
    int r0 = chunk * RC_;
    int rend = r0 + RC_;
    if (rend > Q_) rend = Q_;
    int nrows = rend - r0 + 2;       // pooled rows needed (<= 31)
    int nq = (rend - r0) * G_;

    const float* LAg = la + (size_t)nc * PPAD_;
    const float* PRg = pr + (size_t)nc * PPAD_;
    for (int idx = threadIdx.x; idx < nrows * G_; idx += 512) {
        int rr = idx / G_;
        int cc = (idx - rr * G_) * 4;
        *(float4*)&sLA[rr][cc] = *(const float4*)(LAg + (size_t)(r0 + rr) * PROW_ + cc);
        *(float4*)&sPR[rr][cc] = *(const float4*)(PRg + (size_t)(r0 + rr) * PROW_ + cc);
    }
    __syncthreads();

    int wv = threadIdx.x >> 6;
    int lane = threadIdx.x & 63;
    switch (wv) {
        case 0: tri_lds<0, 2, true, 0, 18>(sLA, nq, lane, cov, nc); break;
        case 1: tri_lds<2, 5, false, 0, 18>(sLA, nq, lane, cov, nc);
                ab_lds<8, 9>(sLA, sPR, nq, lane, cov, nc); break;
        case 2: tri_lds<5, 9, false, 0, 18>(sLA, nq, lane, cov, nc);
                ab_lds<7, 8>(sLA, sPR, nq, lane, cov, nc); break;
        case 3: tri_lds<0, 2, true, 9, 63>(sPR, nq, lane, cov, nc); break;
        case 4: tri_lds<2, 5, false, 9, 63>(sPR, nq, lane, cov, nc);
                ab_lds<6, 7>(sLA, sPR, nq, lane, cov, nc); break;
        case 5: tri_lds<5, 9, false, 9, 63>(sPR, nq, lane, cov, nc);
                ab_lds<5, 6>(sLA, sPR, nq, lane, cov, nc); break;
        case 6: ab_lds<0, 3>(sLA, sPR, nq, lane, cov, nc); break;
        case 7: ab_lds<3, 5>(sLA, sPR, nq, lane, cov, nc); break;
    }
}

// ---------------------------------------------------------------------------
// k_final: per-(n,c) 9x9 algebra. UNCHANGED.
// ---------------------------------------------------------------------------
__global__ __launch_bounds__(128) void k_final(const float* __restrict__ cov,
                                               float* __restrict__ out) {
    __shared__ float red[128];
    int t = threadIdx.x;
    float my = 0.f;
    if (t < NC_) {
        const float* S = cov + t * NCOV_;
        const float Lf = (float)(Q_ * Q_);  // 28561
        float sA[9], sB[9];
#pragma unroll
        for (int d = 0; d < 9; ++d) { sA[d] = S[d]; sB[d] = S[9 + d]; }
        float laC[45], M[45], Cm[81];
        {
            int k = 0;
#pragma unroll
            for (int d = 0; d < 9; ++d)
#pragma unroll
                for (int e = d; e < 9; ++e) {
                    laC[k] = S[18 + k] - sA[d] * sA[e] / Lf;
                    M[k] = S[63 + k] - sB[d] * sB[e] / Lf + (d == e ? EPS_ : 0.f);
                    ++k;
                }
#pragma unroll
            for (int d = 0; d < 9; ++d)
#pragma unroll
                for (int e = 0; e < 9; ++e)
                    Cm[d * 9 + e] = S[108 + d * 9 + e] - sA[d] * sB[e] / Lf;
        }
#pragma unroll
        for (int j = 0; j < 9; ++j) {
            float s = M[tstart(j)];
#pragma unroll
            for (int k = 0; k < j; ++k) { float l = M[tstart(k) + (j - k)]; s -= l * l; }
            float dj = sqrtf(fmaxf(s, 1e-30f));
            M[tstart(j)] = dj;
            float inv = 1.f / dj;
#pragma unroll
            for (int i = j + 1; i < 9; ++i) {
                float s2 = M[tstart(j) + (i - j)];
#pragma unroll
                for (int k = 0; k < j; ++k)
                    s2 -= M[tstart(k) + (i - k)] * M[tstart(k) + (j - k)];
                M[tstart(j) + (i - j)] = s2 * inv;
            }
        }
#pragma unroll
        for (int p = 0; p < 9; ++p) {
#pragma unroll
            for (int i = 0; i < 9; ++i) {
                float s = Cm[p * 9 + i];
#pragma unroll
                for (int k = 0; k < i; ++k)
                    s -= M[tstart(k) + (i - k)] * Cm[p * 9 + k];
                Cm[p * 9 + i] = s / M[tstart(i)];
            }
        }
#pragma unroll
        for (int d = 0; d < 9; ++d)
#pragma unroll
            for (int e = d; e < 9; ++e) {
                float s = 0.f;
#pragma unroll
                for (int i = 0; i < 9; ++i) s += Cm[d * 9 + i] * Cm[e * 9 + i];
                laC[tstart(d) + (e - d)] -= s;
                if (d == e) laC[tstart(d)] += EPS_;
            }
        float rmi = 0.f;
#pragma unroll
        for (int j = 0; j < 9; ++j) {
            float s = laC[tstart(j)];
#pragma unroll
            for (int k = 0; k < j; ++k) { float l = laC[tstart(k) + (j - k)]; s -= l * l; }
            float dj = sqrtf(fmaxf(s, 0.f));
            laC[tstart(j)] = dj;
            float inv = 1.f / fmaxf(dj, 1e-30f);
#pragma unroll
            for (int i = j + 1; i < 9; ++i) {
                float s2 = laC[tstart(j) + (i - j)];
#pragma unroll
                for (int k = 0; k < j; ++k)
                    s2 -= laC[tstart(k) + (i - k)] * laC[tstart(k) + (j - k)];
                laC[tstart(j) + (i - j)] = s2 * inv;
            }
            rmi += __logf(dj + 1e-8f);
        }
        my = rmi;
    }
    red[t] = my;
    __syncthreads();
#pragma unroll
    for (int o = 64; o > 0; o >>= 1) {
        if (t < o) red[t] += red[t + o];
        __syncthreads();
    }
    if (t == 0) {
        float rmi_total = red[0] / 36.f;  // / (N * HALF_D)
        float ce = cov[NC_ * NCOV_ + 0] / cov[NC_ * NCOV_ + 1];
        out[0] = 0.5f * ce + 0.5f * rmi_total;
    }
}

extern "C" void kernel_launch(void* const* d_in, const int* in_sizes, int n_in,
                              void* d_out, int out_size, void* d_ws, size_t ws_size,
                              hipStream_t stream) {
    const float* score = (const float*)d_in[0];
    const int* target = (const int*)d_in[1];
    float* pr = (float*)d_ws;
    float* la = pr + (size_t)NC_ * PPAD_;
    float* cov = la + (size_t)NC_ * PPAD_;              // NC_*NCOV_ + 2 floats
    unsigned* pack = (unsigned*)(cov + NC_ * NCOV_ + 2);
    hipMemsetAsync(cov, 0, (size_t)(NC_ * NCOV_ + 2) * sizeof(float), stream);

    k_bits<<<dim3((N_ * PP_ + 255) / 256), dim3(256), 0, stream>>>(target, pack);
    k_ce<<<dim3(N_ * HW_ / 4 / 256), dim3(256), 0, stream>>>(score, target, cov);
    k_pool<<<dim3((NC_ * P_ * G_ + 255) / 256), dim3(256), 0, stream>>>(score, pack, pr, la);
    k_cov<<<dim3(NC_, 6), dim3(512), 0, stream>>>(la, pr, cov);
    k_final<<<dim3(1), dim3(128), 0, stream>>>(cov, (float*)d_out);
}